// Round 5
// baseline (445.493 us; speedup 1.0000x reference)
//
#include <hip/hip_runtime.h>
#include <hip/hip_cooperative_groups.h>
#include <math.h>

namespace cg = cooperative_groups;

// DigitCaps dynamic routing. B=256, R=1152, C=10, O=16, I=8, 3 iters.
// Single cooperative persistent kernel (256 blocks x 256 thr), 7 grid.sync()s:
//   it 0..2: [softmax+GEMM -> part] sync [reduce+squash -> v/out]
//            (it<2): sync [gtdot: G=X^T.V tile -> LDS -> dot W -> bij] sync
// u_hat (188 MB) never materialized. Fallback to 8-launch path if cooperative
// launch is rejected (e.g. under graph capture).

#define B_ 256
#define R_ 1152
#define N_ 160      // C*O
#define K_ 9216     // R*I
#define NSPLIT 64   // K splits of 144 (18 routes)
#define KBLK 144
#define KC 72       // K per LDS stage (9 routes)

// workspace layout (float offsets)
#define PART_SZ  (4*NSPLIT*64*N_)   // 2,621,440 floats
#define BIJ_SZ   (R_*10)
#define V_SZ     (B_*N_)

// ---------------------------------------------------------------------------
__device__ __forceinline__ void gemm_phase(int blk, int it,
    const float* __restrict__ X, const float* __restrict__ W,
    const float* __restrict__ bij, float* __restrict__ part,
    float* LA, float* LB, float* cs, float* red, float* dsm)
{
    const int tid = threadIdx.x;
    const int ks = blk & 63, bt = blk >> 6;
    const int b0 = bt * 64, k0 = ks * KBLK;
    const int r0 = ks * 18;

    // fused softmax over routes (axis 0), redundant per block
    if (it == 0) {
        if (tid < 180) cs[tid] = 1.0f / 1152.0f;
    } else {
        float dcol[10];
        #pragma unroll
        for (int c = 0; c < 10; ++c) dcol[c] = 0.0f;
        for (int r = tid; r < R_; r += 256) {
            #pragma unroll
            for (int c = 0; c < 10; ++c) dcol[c] += __expf(bij[r * 10 + c]);
        }
        const int lane = tid & 63, wv = tid >> 6;
        #pragma unroll
        for (int c = 0; c < 10; ++c) {
            float s = dcol[c];
            #pragma unroll
            for (int off = 32; off > 0; off >>= 1) s += __shfl_down(s, off);
            if (lane == 0) red[wv * 10 + c] = s;
        }
        __syncthreads();
        if (tid < 10)
            dsm[tid] = red[tid] + red[10 + tid] + red[20 + tid] + red[30 + tid];
        __syncthreads();
        if (tid < 180) {
            int rr = tid / 10, cc = tid - rr * 10;
            cs[tid] = __expf(bij[(r0 + rr) * 10 + cc]) / dsm[cc];
        }
    }

    float acc[4][10];
    #pragma unroll
    for (int i = 0; i < 4; ++i)
        #pragma unroll
        for (int j = 0; j < 10; ++j) acc[i][j] = 0.0f;

    const int rg = tid >> 4;   // 16 row groups x 4 b-rows
    const int cg = tid & 15;   // 16 col groups x 10 n-cols

    for (int st = 0; st < 2; ++st) {
        __syncthreads();
        const int kc = k0 + st * KC;
        // stage A transposed: LA[k][b], 1152 float4
        for (int q = tid; q < 1152; q += 256) {
            int bb = q / 18, kf = q - bb * 18;
            float4 a = *(const float4*)(X + (size_t)(b0 + bb) * K_ + kc + kf * 4);
            LA[(kf * 4 + 0) * 64 + bb] = a.x;
            LA[(kf * 4 + 1) * 64 + bb] = a.y;
            LA[(kf * 4 + 2) * 64 + bb] = a.z;
            LA[(kf * 4 + 3) * 64 + bb] = a.w;
        }
        // stage B from native W (9-route contiguous slice), c_ij-scaled
        const float* Wsl = W + (size_t)(r0 + st * 9) * 1280;
        for (int q = tid; q < 2880; q += 256) {
            int rl = q / 320;
            int rem = q - rl * 320;
            int c = rem >> 5;
            int o = (rem & 31) >> 1;
            int i4 = rem & 1;
            float4 w = *(const float4*)(Wsl + (size_t)q * 4);
            float sc = cs[(st * 9 + rl) * 10 + c];
            int kk = rl * 8 + i4 * 4;
            int nn = c * 16 + o;
            LB[(kk + 0) * 160 + nn] = w.x * sc;
            LB[(kk + 1) * 160 + nn] = w.y * sc;
            LB[(kk + 2) * 160 + nn] = w.z * sc;
            LB[(kk + 3) * 160 + nn] = w.w * sc;
        }
        __syncthreads();
        #pragma unroll 4
        for (int kk = 0; kk < KC; ++kk) {
            float4 a4 = *(const float4*)(&LA[kk * 64 + rg * 4]);
            float av[4] = {a4.x, a4.y, a4.z, a4.w};
            float bv[10];
            #pragma unroll
            for (int j = 0; j < 10; ++j) bv[j] = LB[kk * 160 + cg * 10 + j];
            #pragma unroll
            for (int i = 0; i < 4; ++i)
                #pragma unroll
                for (int j = 0; j < 10; ++j) acc[i][j] += av[i] * bv[j];
        }
    }
    float* P = part + (size_t)(bt * NSPLIT + ks) * (64 * N_);
    #pragma unroll
    for (int i = 0; i < 4; ++i)
        #pragma unroll
        for (int j = 0; j < 10; ++j)
            P[(rg * 4 + i) * N_ + cg * 10 + j] = acc[i][j];
}

// ---------------------------------------------------------------------------
__device__ __forceinline__ void reduce_phase(int gidx,
    const float* __restrict__ part, float* __restrict__ o)
{
    if (gidx < B_ * N_) {
        int b = gidx / N_;
        int bt = b >> 6;
        int local = gidx - bt * (64 * N_);
        const float* p = part + (size_t)bt * NSPLIT * (64 * N_) + local;
        float s = 0.0f;
        #pragma unroll 8
        for (int ks = 0; ks < NSPLIT; ++ks) s += p[(size_t)ks * (64 * N_)];
        o[gidx] = s * fabsf(s) / (1.0f + s * s);   // elementwise squash
    }
}

// ---------------------------------------------------------------------------
__device__ __forceinline__ void gtdot_phase(int blk, int it,
    const float* __restrict__ X, const float* __restrict__ W,
    const float* __restrict__ V, float* __restrict__ bij,
    float* LA, float* LB)
{
    const int tid = threadIdx.x;
    const int k0 = blk * 64;                 // 8 routes per block
    const int rg = tid >> 4, cg = tid & 15;
    float acc[4][10];
    #pragma unroll
    for (int i = 0; i < 4; ++i)
        #pragma unroll
        for (int j = 0; j < 10; ++j) acc[i][j] = 0.0f;

    for (int bt = 0; bt < 4; ++bt) {
        __syncthreads();
        const int b0 = bt * 64;
        #pragma unroll
        for (int j = 0; j < 4; ++j) {        // LA used as X[b][64k]
            int q = j * 256 + tid;
            int bb = q >> 4, kf = q & 15;
            *(float4*)(&LA[bb * 64 + kf * 4]) =
                *(const float4*)(X + (size_t)(b0 + bb) * K_ + k0 + kf * 4);
        }
        #pragma unroll
        for (int j = 0; j < 10; ++j) {       // LB used as V[b][160], stride 164
            int q = j * 256 + tid;
            int bb = q / 40, nf = (q - bb * 40) * 4;
            *(float4*)(&LB[bb * 164 + nf]) =
                *(const float4*)(V + (size_t)(b0 + bb) * N_ + nf);
        }
        __syncthreads();
        #pragma unroll 4
        for (int b = 0; b < 64; ++b) {
            float4 a4 = *(const float4*)(&LA[b * 64 + rg * 4]);
            float av[4] = {a4.x, a4.y, a4.z, a4.w};
            float bv[10];
            #pragma unroll
            for (int j = 0; j < 10; ++j) bv[j] = LB[b * 164 + cg * 10 + j];
            #pragma unroll
            for (int i = 0; i < 4; ++i)
                #pragma unroll
                for (int j = 0; j < 10; ++j) acc[i][j] += av[i] * bv[j];
        }
    }
    // G tile -> LDS (reuse LB, stride 164 keeps writes 2-way)
    __syncthreads();
    #pragma unroll
    for (int i = 0; i < 4; ++i)
        #pragma unroll
        for (int j = 0; j < 10; ++j)
            LB[(rg * 4 + i) * 164 + cg * 10 + j] = acc[i][j];
    __syncthreads();
    if (tid < 80) {
        int rl = tid / 10, c = tid - rl * 10;
        int r = (k0 >> 3) + rl;
        const float4* wp4 = (const float4*)(W + (size_t)r * 1280 + c * 128);
        float s = 0.0f;
        #pragma unroll
        for (int o = 0; o < 16; ++o) {
            float4 wa = wp4[o * 2], wb = wp4[o * 2 + 1];
            int nn = c * 16 + o, kk = rl * 8;
            s += wa.x * LB[(kk + 0) * 164 + nn] + wa.y * LB[(kk + 1) * 164 + nn] +
                 wa.z * LB[(kk + 2) * 164 + nn] + wa.w * LB[(kk + 3) * 164 + nn] +
                 wb.x * LB[(kk + 4) * 164 + nn] + wb.y * LB[(kk + 5) * 164 + nn] +
                 wb.z * LB[(kk + 6) * 164 + nn] + wb.w * LB[(kk + 7) * 164 + nn];
        }
        if (it == 0) bij[r * 10 + c] = s * (1.0f / B_);
        else         bij[r * 10 + c] += s * (1.0f / B_);
    }
}

// ---------------------------------------------------------------------------
__global__ __launch_bounds__(256, 2) void k_caps(const float* __restrict__ X,
                                                 const float* __restrict__ W,
                                                 float* part, float* bij,
                                                 float* vws, float* out) {
    __shared__ float LA[KC * 64];    // 18 KB
    __shared__ float LB[KC * 160];   // 45 KB (gtdot: 64x164 = 10496 fits)
    __shared__ float cs[180];
    __shared__ float red[40];
    __shared__ float dsm[10];
    cg::grid_group g = cg::this_grid();
    const int blk = blockIdx.x;
    for (int it = 0; it < 3; ++it) {
        gemm_phase(blk, it, X, W, bij, part, LA, LB, cs, red, dsm);
        g.sync();
        reduce_phase(blk * 256 + threadIdx.x, part, (it == 2) ? out : vws);
        if (it < 2) {
            g.sync();
            if (blk < 144) gtdot_phase(blk, it, X, W, vws, bij, LA, LB);
            g.sync();
        }
    }
}

// ---- non-cooperative fallback wrappers ------------------------------------
__global__ __launch_bounds__(256, 2) void k_p1(const float* __restrict__ X,
                                               const float* __restrict__ W,
                                               const float* __restrict__ bij,
                                               float* part, int it) {
    __shared__ float LA[KC * 64];
    __shared__ float LB[KC * 160];
    __shared__ float cs[180];
    __shared__ float red[40];
    __shared__ float dsm[10];
    gemm_phase(blockIdx.x, it, X, W, bij, part, LA, LB, cs, red, dsm);
}
__global__ void k_p2(const float* __restrict__ part, float* __restrict__ o) {
    reduce_phase(blockIdx.x * 256 + threadIdx.x, part, o);
}
__global__ __launch_bounds__(256, 2) void k_p3(const float* __restrict__ X,
                                               const float* __restrict__ W,
                                               const float* __restrict__ V,
                                               float* bij, int it) {
    __shared__ float LA[KC * 64];
    __shared__ float LB[KC * 160];
    gtdot_phase(blockIdx.x, it, X, W, V, bij, LA, LB);
}

// ---------------------------------------------------------------------------
extern "C" void kernel_launch(void* const* d_in, const int* in_sizes, int n_in,
                              void* d_out, int out_size, void* d_ws, size_t ws_size,
                              hipStream_t stream) {
    const float* x = (const float*)d_in[0];   // (256, 1152, 8)
    const float* W = (const float*)d_in[1];   // (1152, 10, 16, 8)
    float* ws   = (float*)d_ws;
    float* part = ws;
    float* bij  = ws + PART_SZ;
    float* vws  = bij + BIJ_SZ;
    float* outf = (float*)d_out;

    void* args[] = {(void*)&x, (void*)&W, (void*)&part,
                    (void*)&bij, (void*)&vws, (void*)&outf};
    hipError_t e = hipLaunchCooperativeKernel((const void*)k_caps, dim3(256),
                                              dim3(256), args, 0, stream);
    if (e != hipSuccess) {
        // fallback: 8-launch classic path (same math, same workspace)
        for (int it = 0; it < 3; ++it) {
            k_p1<<<256, 256, 0, stream>>>(x, W, bij, part, it);
            k_p2<<<160, 256, 0, stream>>>(part, (it == 2) ? outf : vws);
            if (it < 2) k_p3<<<144, 256, 0, stream>>>(x, W, vws, bij, it);
        }
    }
}

// Round 6
// 201.699 us; speedup vs baseline: 2.2087x; 2.2087x over previous
//
#include <hip/hip_runtime.h>
#include <math.h>

// DigitCaps dynamic routing. B=256, R=1152, C=10, O=16, I=8, 3 iters.
// 8 launches (coop grid.sync measured ~45us/sync on MI355X — abandoned).
// Bottleneck is per-CU LDS instruction throughput -> all inner loops
// restructured for vectorized LDS reads (b128/b64) and bigger thread tiles.
//   it 0..2: k_gemm  (fused softmax; 128 K-splits x 2 b-tiles; 8b x 10n/thread)
//            k_reduce (128-way split-K reduce + squash)
//   it 0..1: k_gtdot (G=X^T.V 72k x 160n tile in regs -> LDS -> W-dot ->
//            atomicAdd bij; 2 b-halves; 9k x 5n/thread)

#define B_ 256
#define R_ 1152
#define N_ 160      // C*O
#define K_ 9216     // R*I
#define NS 128      // K splits of 72 (9 routes)
#define KB 72
#define KC 24       // K per LDS stage (3 routes)

// workspace layout (float offsets)
#define PART_SZ (2*NS*128*N_)   // 5,242,880 floats (21 MB)
#define BIJ_SZ  (R_*10)
#define V_SZ    (B_*N_)

// ---------------------------------------------------------------------------
// part[bt,ks][128x160] = X[128 b][72 k] * (softmax_r(bij) ⊙ W)[72 k][160 n]
// grid 256 = (ks 0..127) x (bt 0..1); thread tile 8b x 10n
__global__ __launch_bounds__(256) void k_gemm(const float* __restrict__ X,
                                              const float* __restrict__ W,
                                              float* __restrict__ bij,
                                              float* __restrict__ part,
                                              int it) {
    __shared__ float As[KC * 128];   // [k][b] transposed, 12 KB
    __shared__ float Bs[KC * 192];   // [k][16 groups of 12], 18.4 KB
    __shared__ float cs[90];         // c_ij for this block's 9 routes
    __shared__ float red[40];
    __shared__ float dsm[10];
    const int tid = threadIdx.x;
    const int ks = blockIdx.x >> 1, bt = blockIdx.x & 1;
    const int b0 = bt * 128, k0 = ks * KB, r0 = ks * 9;

    // ---- fused softmax over routes (axis 0), redundant per block ----
    if (it == 0) {
        if (tid < 90) cs[tid] = 1.0f / 1152.0f;
        if (bt == 0 && tid < 90) bij[r0 * 10 + tid] = 0.0f;  // init for gtdot
    } else {
        float dcol[10];
        #pragma unroll
        for (int c = 0; c < 10; ++c) dcol[c] = 0.0f;
        for (int r = tid; r < R_; r += 256) {
            #pragma unroll
            for (int c = 0; c < 10; ++c) dcol[c] += __expf(bij[r * 10 + c]);
        }
        const int lane = tid & 63, wv = tid >> 6;
        #pragma unroll
        for (int c = 0; c < 10; ++c) {
            float s = dcol[c];
            #pragma unroll
            for (int off = 32; off > 0; off >>= 1) s += __shfl_down(s, off);
            if (lane == 0) red[wv * 10 + c] = s;
        }
        __syncthreads();
        if (tid < 10)
            dsm[tid] = red[tid] + red[10 + tid] + red[20 + tid] + red[30 + tid];
        __syncthreads();
        if (tid < 90) {
            int rr = tid / 10, cc = tid - rr * 10;
            cs[tid] = __expf(bij[(r0 + rr) * 10 + cc]) / dsm[cc];
        }
    }

    float acc[8][10];
    #pragma unroll
    for (int i = 0; i < 8; ++i)
        #pragma unroll
        for (int j = 0; j < 10; ++j) acc[i][j] = 0.0f;

    const int rg = tid >> 4;   // 16 groups x 8 b-rows
    const int cg = tid & 15;   // 16 groups x 10 n-cols

    for (int st = 0; st < 3; ++st) {
        __syncthreads();
        const int kc = k0 + st * KC;
        // stage A transposed: 768 float4 (3/thread)
        #pragma unroll
        for (int j = 0; j < 3; ++j) {
            int q = j * 256 + tid;
            int bb = q / 6, kf = q - bb * 6;
            float4 a = *(const float4*)(X + (size_t)(b0 + bb) * K_ + kc + kf * 4);
            As[(kf * 4 + 0) * 128 + bb] = a.x;
            As[(kf * 4 + 1) * 128 + bb] = a.y;
            As[(kf * 4 + 2) * 128 + bb] = a.z;
            As[(kf * 4 + 3) * 128 + bb] = a.w;
        }
        // stage B from native W (3-route slice), c_ij-scaled, 12-padded groups
        const float* Wsl = W + (size_t)(r0 + st * 3) * 1280;
        #pragma unroll
        for (int j = 0; j < 4; ++j) {
            int q = j * 256 + tid;        // float4 idx < 960
            if (q < 960) {
                int rl = q / 320;
                int rem = q - rl * 320;
                int c = rem >> 5;
                int o = (rem & 31) >> 1;
                int i4 = rem & 1;
                float4 w = *(const float4*)(Wsl + (size_t)q * 4);
                float sc = cs[(st * 3 + rl) * 10 + c];
                int nn = c * 16 + o;
                int grp = nn / 10;
                int pos = grp * 12 + (nn - grp * 10);
                int kk = rl * 8 + i4 * 4;
                Bs[(kk + 0) * 192 + pos] = w.x * sc;
                Bs[(kk + 1) * 192 + pos] = w.y * sc;
                Bs[(kk + 2) * 192 + pos] = w.z * sc;
                Bs[(kk + 3) * 192 + pos] = w.w * sc;
            }
        }
        __syncthreads();
        #pragma unroll 6
        for (int kk = 0; kk < KC; ++kk) {
            float4 a0 = *(const float4*)(&As[kk * 128 + rg * 8]);
            float4 a1 = *(const float4*)(&As[kk * 128 + rg * 8 + 4]);
            float4 v0 = *(const float4*)(&Bs[kk * 192 + cg * 12]);
            float4 v1 = *(const float4*)(&Bs[kk * 192 + cg * 12 + 4]);
            float2 v2 = *(const float2*)(&Bs[kk * 192 + cg * 12 + 8]);
            float av[8] = {a0.x, a0.y, a0.z, a0.w, a1.x, a1.y, a1.z, a1.w};
            float bv[10] = {v0.x, v0.y, v0.z, v0.w, v1.x, v1.y, v1.z, v1.w,
                            v2.x, v2.y};
            #pragma unroll
            for (int i = 0; i < 8; ++i)
                #pragma unroll
                for (int j = 0; j < 10; ++j) acc[i][j] += av[i] * bv[j];
        }
    }
    float* P = part + (size_t)(bt * NS + ks) * (128 * N_);
    #pragma unroll
    for (int i = 0; i < 8; ++i)
        #pragma unroll
        for (int j = 0; j < 10; ++j)
            P[(rg * 8 + i) * N_ + cg * 10 + j] = acc[i][j];
}

// ---------------------------------------------------------------------------
__global__ void k_reduce(const float* __restrict__ part, float* __restrict__ out) {
    int g = blockIdx.x * 256 + threadIdx.x;   // < 40960
    int b = g / N_;
    int bt = b >> 7;
    int local = g - bt * (128 * N_);
    const float* p = part + (size_t)bt * NS * (128 * N_) + local;
    float s = 0.0f;
    #pragma unroll 8
    for (int ks = 0; ks < NS; ++ks) s += p[(size_t)ks * (128 * N_)];
    out[g] = s * fabsf(s) / (1.0f + s * s);   // elementwise squash
}

// ---------------------------------------------------------------------------
// per block (kt 0..127: 72 k-rows = 9 routes; bh 0..1: 128 b):
//   G_partial[72x160] = sum_{b-half} X^T V  (regs, 4 b-stages of 32)
//   -> LDS -> bij[r,c] += (1/B) sum_{o,i} W[r,c,o,i]*G[...]  (atomicAdd)
// thread tile 9k x 5n; X 12-padded vec reads; V transposed [n][33] scalar
__global__ __launch_bounds__(256) void k_gtdot(const float* __restrict__ X,
                                               const float* __restrict__ W,
                                               const float* __restrict__ V,
                                               float* __restrict__ bij) {
    __shared__ float L[72 * 165];    // 47.5 KB; union: staging | G-tile
    float* Xs = L;                   // [32][96]  (8 groups x 12)
    float* Vs = L + 3072;            // [160][33] transposed
    float* LG = L;                   // [72][165]
    const int tid = threadIdx.x;
    const int kt = blockIdx.x >> 1, bh = blockIdx.x & 1;
    const int k0 = kt * 72, r0 = kt * 9, b0 = bh * 128;
    const int rg = tid >> 5;   // 8 groups x 9 k-rows
    const int cg = tid & 31;   // 32 groups x 5 n-cols
    float acc[9][5];
    #pragma unroll
    for (int i = 0; i < 9; ++i)
        #pragma unroll
        for (int j = 0; j < 5; ++j) acc[i][j] = 0.0f;

    for (int sb = 0; sb < 4; ++sb) {
        __syncthreads();
        const int bb0 = b0 + sb * 32;
        // X: 576 float4 -> Xs[b][12-padded k-groups]
        #pragma unroll
        for (int j = 0; j < 3; ++j) {
            int q = j * 256 + tid;
            if (q < 576) {
                int bb = q / 18, kf = q - bb * 18;
                float4 a = *(const float4*)(X + (size_t)(bb0 + bb) * K_ + k0 + kf * 4);
                float c4[4] = {a.x, a.y, a.z, a.w};
                #pragma unroll
                for (int m = 0; m < 4; ++m) {
                    int kk = kf * 4 + m;
                    int gp = kk / 9;
                    Xs[bb * 96 + gp * 12 + (kk - gp * 9)] = c4[m];
                }
            }
        }
        // V: 1280 float4 -> Vs[n][b] transposed, stride 33
        #pragma unroll
        for (int j = 0; j < 5; ++j) {
            int q = j * 256 + tid;
            int bb = q / 40, nf = q - bb * 40;
            float4 v = *(const float4*)(V + (size_t)(bb0 + bb) * N_ + nf * 4);
            int n = nf * 4;
            Vs[(n + 0) * 33 + bb] = v.x;
            Vs[(n + 1) * 33 + bb] = v.y;
            Vs[(n + 2) * 33 + bb] = v.z;
            Vs[(n + 3) * 33 + bb] = v.w;
        }
        __syncthreads();
        #pragma unroll 4
        for (int b = 0; b < 32; ++b) {
            float4 x0 = *(const float4*)(&Xs[b * 96 + rg * 12]);
            float4 x1 = *(const float4*)(&Xs[b * 96 + rg * 12 + 4]);
            float x8 = Xs[b * 96 + rg * 12 + 8];
            float xr[9] = {x0.x, x0.y, x0.z, x0.w, x1.x, x1.y, x1.z, x1.w, x8};
            float bv[5];
            #pragma unroll
            for (int j = 0; j < 5; ++j) bv[j] = Vs[(cg * 5 + j) * 33 + b];
            #pragma unroll
            for (int i = 0; i < 9; ++i)
                #pragma unroll
                for (int j = 0; j < 5; ++j) acc[i][j] += xr[i] * bv[j];
        }
    }
    // G tile -> LDS (overwrites staging), stride 165 breaks pow2 banks
    __syncthreads();
    #pragma unroll
    for (int i = 0; i < 9; ++i)
        #pragma unroll
        for (int j = 0; j < 5; ++j)
            LG[(rg * 9 + i) * 165 + cg * 5 + j] = acc[i][j];
    __syncthreads();
    if (tid < 90) {
        int rl = tid / 10, c = tid - rl * 10;
        int r = r0 + rl;
        const float4* wp = (const float4*)(W + (size_t)r * 1280 + c * 128);
        float s = 0.0f;
        #pragma unroll
        for (int o = 0; o < 16; ++o) {
            float4 wa = wp[o * 2], wb = wp[o * 2 + 1];
            const float* g = &LG[(rl * 8) * 165 + c * 16 + o];
            s += wa.x * g[0]       + wa.y * g[165]     + wa.z * g[2 * 165] +
                 wa.w * g[3 * 165] + wb.x * g[4 * 165] + wb.y * g[5 * 165] +
                 wb.z * g[6 * 165] + wb.w * g[7 * 165];
        }
        atomicAdd(&bij[r * 10 + c], s * (1.0f / B_));
    }
}

// ---------------------------------------------------------------------------
extern "C" void kernel_launch(void* const* d_in, const int* in_sizes, int n_in,
                              void* d_out, int out_size, void* d_ws, size_t ws_size,
                              hipStream_t stream) {
    const float* x = (const float*)d_in[0];   // (256, 1152, 8)
    const float* W = (const float*)d_in[1];   // (1152, 10, 16, 8)
    float* ws   = (float*)d_ws;
    float* part = ws;
    float* bij  = ws + PART_SZ;
    float* vws  = bij + BIJ_SZ;
    float* outf = (float*)d_out;

    for (int it = 0; it < 3; ++it) {
        k_gemm<<<256, 256, 0, stream>>>(x, W, bij, part, it);
        k_reduce<<<160, 256, 0, stream>>>(part, (it == 2) ? outf : vws);
        if (it < 2) k_gtdot<<<256, 256, 0, stream>>>(x, W, vws, bij);
    }
}